// Round 5
// baseline (1262.198 us; speedup 1.0000x reference)
//
#include <hip/hip_runtime.h>
#include <math.h>

#define D 128
#define NF 10
#define N_IP 20000
#define N_CONN 100000
#define NE 200000
#define T_ROUNDS 3

typedef unsigned short u16;
using bf16x8 = __attribute__((ext_vector_type(8))) short;
using floatx4 = __attribute__((ext_vector_type(4))) float;

__device__ inline u16 f2bf(float f) {
  union { float f; unsigned u; } v; v.f = f;
  unsigned u = v.u;
  return (u16)((u + 0x7fffu + ((u >> 16) & 1u)) >> 16);  // RNE
}

__device__ inline bf16x8 pack8(float4 a, float4 b) {
  bf16x8 r;
  r[0] = (short)f2bf(a.x); r[1] = (short)f2bf(a.y);
  r[2] = (short)f2bf(a.z); r[3] = (short)f2bf(a.w);
  r[4] = (short)f2bf(b.x); r[5] = (short)f2bf(b.y);
  r[6] = (short)f2bf(b.z); r[7] = (short)f2bf(b.w);
  return r;
}

__device__ inline float fsigmoid(float s) { return 1.f / (1.f + __expf(-s)); }
__device__ inline float ftanh(float a) {
  a = fminf(fmaxf(a, -15.f), 15.f);
  float e = __expf(2.f * a);
  return (e - 1.f) / (e + 1.f);
}

// ---------------- utility kernels ----------------

__global__ void k_fill1(float* p, int n4) {
  int i = blockIdx.x * blockDim.x + threadIdx.x;
  if (i < n4) ((float4*)p)[i] = make_float4(1.f, 1.f, 1.f, 1.f);
}

__global__ void k_init_conn(float* __restrict__ cs, const float* __restrict__ feat) {
  int i = blockIdx.x * blockDim.x + threadIdx.x;
  if (i >= N_CONN * D) return;
  int r = i >> 7, j = i & 127;
  cs[i] = (j < NF) ? feat[r * NF + j] : 0.f;
}

__global__ void k_count(const int* __restrict__ d1, const int* __restrict__ d2,
                        int* __restrict__ c1, int* __restrict__ c2) {
  int e = blockIdx.x * blockDim.x + threadIdx.x;
  if (e >= NE) return;
  atomicAdd(&c1[d1[e]], 1);
  atomicAdd(&c2[d2[e]], 1);
}

// GRU weights: 128x384 fp32 -> [col][k] 384x128 bf16
__global__ void k_prep_w(const float* __restrict__ W, u16* __restrict__ Wb) {
  int i = blockIdx.x * blockDim.x + threadIdx.x;
  if (i >= 384 * 128) return;
  int col = i >> 7, k = i & 127;
  Wb[i] = f2bf(W[k * 384 + col]);
}

// message weight bottom half: W[128..255][0..127] fp32 -> [col][k] 128x128 bf16
__global__ void k_prep_w128(const float* __restrict__ W, u16* __restrict__ Wb) {
  int i = blockIdx.x * blockDim.x + threadIdx.x;
  if (i >= 128 * 128) return;
  int col = i >> 7, k = i & 127;
  Wb[i] = f2bf(W[(128 + k) * 128 + col]);
}

// ---------------- parallel 3-pass exclusive scan ----------------
__global__ void k_scan_part(const int* __restrict__ cnt, int* __restrict__ bsum, int n) {
  int t = threadIdx.x;  // 256
  int base = blockIdx.x * 1024 + t * 4;
  int s = 0;
#pragma unroll
  for (int i = 0; i < 4; i++) { int j = base + i; if (j < n) s += cnt[j]; }
  for (int d = 32; d > 0; d >>= 1) s += __shfl_xor(s, d, 64);
  __shared__ int wred[4];
  int lane = t & 63, wv = t >> 6;
  if (lane == 0) wred[wv] = s;
  __syncthreads();
  if (t == 0) bsum[blockIdx.x] = wred[0] + wred[1] + wred[2] + wred[3];
}

__global__ void k_scan_mid(int* __restrict__ bsum, int m) {
  int t = threadIdx.x;
  int v = (t < m) ? bsum[t] : 0;
  int lane = t & 63, wv = t >> 6;
  int x = v;
  for (int d = 1; d < 64; d <<= 1) { int y = __shfl_up(x, d, 64); if (lane >= d) x += y; }
  __shared__ int wsum[4];
  if (lane == 63) wsum[wv] = x;
  __syncthreads();
  int add = 0;
  for (int i = 0; i < wv; i++) add += wsum[i];
  int ex = add + x - v;
  if (t < m) bsum[t] = ex;
}

__global__ void k_scan_final(const int* __restrict__ cnt, const int* __restrict__ bsum,
                             int* __restrict__ off, int n) {
  int t = threadIdx.x;
  int base = blockIdx.x * 1024 + t * 4;
  int vals[4]; int s = 0;
#pragma unroll
  for (int i = 0; i < 4; i++) {
    int j = base + i;
    vals[i] = (j < n) ? cnt[j] : 0;
    s += vals[i];
  }
  int lane = t & 63, wv = t >> 6;
  int x = s;
  for (int d = 1; d < 64; d <<= 1) { int y = __shfl_up(x, d, 64); if (lane >= d) x += y; }
  __shared__ int wsum[4];
  if (lane == 63) wsum[wv] = x;
  __syncthreads();
  int add = 0;
  for (int i = 0; i < wv; i++) add += wsum[i];
  int run = add + x - s + bsum[blockIdx.x];
#pragma unroll
  for (int i = 0; i < 4; i++) {
    int j = base + i;
    if (j < n) off[j] = run;
    run += vals[i];
  }
}

__global__ void k_copyint(const int* __restrict__ a, int* __restrict__ b, int n) {
  int i = blockIdx.x * blockDim.x + threadIdx.x;
  if (i < n) b[i] = a[i];
}

__global__ void k_scatter(const int* __restrict__ s1, const int* __restrict__ d1,
                          const int* __restrict__ s2, const int* __restrict__ d2,
                          int* __restrict__ cur1, int* __restrict__ cur2,
                          int* __restrict__ o1, int* __restrict__ o2) {
  int e = blockIdx.x * blockDim.x + threadIdx.x;
  if (e >= NE) return;
  int p1 = atomicAdd(&cur1[d1[e]], 1);
  o1[p1] = s1[e];
  int p2 = atomicAdd(&cur2[d2[e]], 1);
  o2[p2] = s2[e];
}

// ---------------- fused Q-GEMM + gather-mean ----------------
// Block = 64 nodes. Q = S[64,128] @ Wb^T (+bias) via MFMA (weights bf16
// [col][k], XOR-swizzled in LDS); Q bounced through LDS (fp32, stride 132);
// then mean over edges of relu(P[src] + Q[node]) -> outm. Q never hits HBM.
__global__ __launch_bounds__(256) void k_qgather(
    const float* __restrict__ S, const u16* __restrict__ Wb,
    const float* __restrict__ bias, const float* __restrict__ P,
    const int* __restrict__ srcs, const int* __restrict__ off,
    const int* __restrict__ cnt, float* __restrict__ outm, int nnodes) {
  __shared__ __align__(16) char smem[64 * 132 * 4];  // 33792 B
  u16* Wls = (u16*)smem;       // 128 cols x 128 k bf16 (32768 B), swizzled
  float* Qls = (float*)smem;   // 64 rows x 132 fp32 (after W consumed)
  const int tid = threadIdx.x, wv = tid >> 6, lane = tid & 63;
  const int lrow = lane & 15, quad = lane >> 4;
  const int bm = blockIdx.x * 64;

  // stage W (coalesced 16B, swizzle granule ^= col&15)
#pragma unroll
  for (int i = 0; i < 8; i++) {
    int task = i * 256 + tid;       // 2048 granule tasks
    int col = task >> 4, gr = task & 15;
    uint4 v = *(const uint4*)(Wb + (size_t)col * 128 + gr * 8);
    *(uint4*)(Wls + (size_t)col * 128 + ((gr ^ (col & 15)) * 8)) = v;
  }
  // A-frags: wave's 16 rows of S, fp32 -> bf16
  const int arow = bm + wv * 16 + lrow;
  const bool arv = arow < nnodes;
  bf16x8 ax[4];
  {
    const float* xp = S + (size_t)arow * 128 + quad * 8;
#pragma unroll
    for (int ks = 0; ks < 4; ks++) {
      float4 a0 = make_float4(0, 0, 0, 0), a1 = a0;
      if (arv) {
        a0 = *(const float4*)(xp + ks * 32);
        a1 = *(const float4*)(xp + ks * 32 + 4);
      }
      ax[ks] = pack8(a0, a1);
    }
  }
  __syncthreads();
  floatx4 acc[8];
#pragma unroll
  for (int ct = 0; ct < 8; ct++) acc[ct] = {0.f, 0.f, 0.f, 0.f};
#pragma unroll
  for (int ks = 0; ks < 4; ks++) {
#pragma unroll
    for (int ct = 0; ct < 8; ct++) {
      int col = ct * 16 + lrow;
      bf16x8 b = *(const bf16x8*)(Wls + (size_t)col * 128 + (((4 * ks + quad) ^ lrow) * 8));
      acc[ct] = __builtin_amdgcn_mfma_f32_16x16x32_bf16(ax[ks], b, acc[ct], 0, 0, 0);
    }
  }
  __syncthreads();  // all W reads done; reuse smem as Q
#pragma unroll
  for (int ct = 0; ct < 8; ct++) {
    int col = ct * 16 + lrow;
    float bv = bias[col];
#pragma unroll
    for (int reg = 0; reg < 4; reg++) {
      int lr = wv * 16 + quad * 4 + reg;  // local row
      Qls[(size_t)lr * 132 + col] = acc[ct][reg] + bv;
    }
  }
  __syncthreads();
  // gather: 64 nodes x 32 col-groups = 2048 tasks
#pragma unroll
  for (int it = 0; it < 8; it++) {
    int task = it * 256 + tid;
    int nl = task >> 5, c4 = (task & 31) << 2;
    int node = bm + nl;
    if (node >= nnodes) continue;
    float* qp = Qls + (size_t)nl * 132 + c4;
    float qx = qp[0], qy = qp[1], qz = qp[2], qw = qp[3];
    float ax2 = 0.f, ay = 0.f, az = 0.f, aw = 0.f;
    int o = off[node], n = cnt[node];
    int i = 0;
    for (; i + 4 <= n; i += 4) {
      int s0 = srcs[o + i], s1 = srcs[o + i + 1], s2 = srcs[o + i + 2], s3 = srcs[o + i + 3];
      float4 p0 = *(const float4*)(P + (size_t)s0 * D + c4);
      float4 p1 = *(const float4*)(P + (size_t)s1 * D + c4);
      float4 p2 = *(const float4*)(P + (size_t)s2 * D + c4);
      float4 p3 = *(const float4*)(P + (size_t)s3 * D + c4);
      ax2 += fmaxf(p0.x + qx, 0.f) + fmaxf(p1.x + qx, 0.f) + fmaxf(p2.x + qx, 0.f) + fmaxf(p3.x + qx, 0.f);
      ay += fmaxf(p0.y + qy, 0.f) + fmaxf(p1.y + qy, 0.f) + fmaxf(p2.y + qy, 0.f) + fmaxf(p3.y + qy, 0.f);
      az += fmaxf(p0.z + qz, 0.f) + fmaxf(p1.z + qz, 0.f) + fmaxf(p2.z + qz, 0.f) + fmaxf(p3.z + qz, 0.f);
      aw += fmaxf(p0.w + qw, 0.f) + fmaxf(p1.w + qw, 0.f) + fmaxf(p2.w + qw, 0.f) + fmaxf(p3.w + qw, 0.f);
    }
    for (; i + 2 <= n; i += 2) {
      int s0 = srcs[o + i], s1 = srcs[o + i + 1];
      float4 p0 = *(const float4*)(P + (size_t)s0 * D + c4);
      float4 p1 = *(const float4*)(P + (size_t)s1 * D + c4);
      ax2 += fmaxf(p0.x + qx, 0.f) + fmaxf(p1.x + qx, 0.f);
      ay += fmaxf(p0.y + qy, 0.f) + fmaxf(p1.y + qy, 0.f);
      az += fmaxf(p0.z + qz, 0.f) + fmaxf(p1.z + qz, 0.f);
      aw += fmaxf(p0.w + qw, 0.f) + fmaxf(p1.w + qw, 0.f);
    }
    if (i < n) {
      int s0 = srcs[o + i];
      float4 p0 = *(const float4*)(P + (size_t)s0 * D + c4);
      ax2 += fmaxf(p0.x + qx, 0.f);
      ay += fmaxf(p0.y + qy, 0.f);
      az += fmaxf(p0.z + qz, 0.f);
      aw += fmaxf(p0.w + qw, 0.f);
    }
    float inv = 1.f / fmaxf((float)n, 1.f);
    *(float4*)(outm + (size_t)node * D + c4) =
        make_float4(ax2 * inv, ay * inv, az * inv, aw * inv);
  }
}

// ---------------- fused GRU v3: pipelined weight staging, swizzled LDS ----------------
__global__ __launch_bounds__(256) void k_gru_fused(
    const float* __restrict__ X, const u16* __restrict__ Wxb,
    const u16* __restrict__ Whb, const float* __restrict__ bias,
    float* __restrict__ H, int rows) {
  __shared__ __align__(16) u16 Ls[6 * 32 * 128];  // 49152 B, swizzled
  const int tid = threadIdx.x, wv = tid >> 6, lane = tid & 63;
  const int lrow = lane & 15, quad = lane >> 4;
  const int bm = blockIdx.x * 64;
  const int arow = bm + wv * 16 + lrow;
  const bool arv = arow < rows;
  bf16x8 ax[4], ah[4];
  {
    const float* xp = X + (size_t)arow * 128 + quad * 8;
    const float* hp = H + (size_t)arow * 128 + quad * 8;
#pragma unroll
    for (int ks = 0; ks < 4; ks++) {
      float4 a0 = make_float4(0, 0, 0, 0), a1 = a0, b0 = a0, b1 = a0;
      if (arv) {
        a0 = *(const float4*)(xp + ks * 32);
        a1 = *(const float4*)(xp + ks * 32 + 4);
        b0 = *(const float4*)(hp + ks * 32);
        b1 = *(const float4*)(hp + ks * 32 + 4);
      }
      ax[ks] = pack8(a0, a1);
      ah[ks] = pack8(b0, b1);
    }
  }
  const int crow = bm + wv * 16 + quad * 4;
  const int scol = tid >> 4;       // 0..15
  const int sgr = tid & 15;        // granule 0..15
  // prefetch chunk 0
  uint4 v[12];
#pragma unroll
  for (int seg = 0; seg < 6; seg++) {
    const u16* g = (seg < 3 ? Wxb : Whb) + (size_t)((seg % 3) * 128) * 128;
    v[2 * seg] = *(const uint4*)(g + (size_t)scol * 128 + sgr * 8);
    v[2 * seg + 1] = *(const uint4*)(g + (size_t)(scol + 16) * 128 + sgr * 8);
  }
  for (int ch = 0; ch < 4; ch++) {
    __syncthreads();  // prev chunk's LDS readers done
#pragma unroll
    for (int seg = 0; seg < 6; seg++) {
      u16* base = Ls + seg * 32 * 128;
      *(uint4*)(base + scol * 128 + ((sgr ^ scol) * 8)) = v[2 * seg];
      *(uint4*)(base + (scol + 16) * 128 + ((sgr ^ scol) * 8)) = v[2 * seg + 1];
    }
    __syncthreads();
    if (ch < 3) {  // prefetch next chunk; latency overlaps MFMA+epilogue
#pragma unroll
      for (int seg = 0; seg < 6; seg++) {
        const u16* g = (seg < 3 ? Wxb : Whb) +
                       (size_t)((seg % 3) * 128 + (ch + 1) * 32) * 128;
        v[2 * seg] = *(const uint4*)(g + (size_t)scol * 128 + sgr * 8);
        v[2 * seg + 1] = *(const uint4*)(g + (size_t)(scol + 16) * 128 + sgr * 8);
      }
    }
    floatx4 accx[2][3], acch[2][3];
#pragma unroll
    for (int t = 0; t < 2; t++)
#pragma unroll
      for (int g = 0; g < 3; g++) {
        accx[t][g] = {0.f, 0.f, 0.f, 0.f};
        acch[t][g] = {0.f, 0.f, 0.f, 0.f};
      }
#pragma unroll
    for (int ks = 0; ks < 4; ks++) {
      int posu = ((4 * ks + quad) ^ lrow) * 8;
#pragma unroll
      for (int t = 0; t < 2; t++) {
        int cIdx = t * 16 + lrow;
#pragma unroll
        for (int g = 0; g < 3; g++) {
          bf16x8 bx = *(const bf16x8*)(Ls + (size_t)(g * 32 + cIdx) * 128 + posu);
          bf16x8 bh = *(const bf16x8*)(Ls + (size_t)((3 + g) * 32 + cIdx) * 128 + posu);
          accx[t][g] = __builtin_amdgcn_mfma_f32_16x16x32_bf16(ax[ks], bx, accx[t][g], 0, 0, 0);
          acch[t][g] = __builtin_amdgcn_mfma_f32_16x16x32_bf16(ah[ks], bh, acch[t][g], 0, 0, 0);
        }
      }
    }
#pragma unroll
    for (int t = 0; t < 2; t++) {
      int hcol = ch * 32 + t * 16 + lrow;
      float bxz = bias[hcol];
      float bxr = bias[128 + hcol];
      float bxh = bias[256 + hcol];
      float bhz = bias[384 + hcol];
      float bhr = bias[384 + 128 + hcol];
      float bhh = bias[384 + 256 + hcol];
#pragma unroll
      for (int reg = 0; reg < 4; reg++) {
        int r = crow + reg;
        if (r < rows) {
          float xz = accx[t][0][reg] + bxz;
          float xr = accx[t][1][reg] + bxr;
          float xh = accx[t][2][reg] + bxh;
          float hz = acch[t][0][reg] + bhz;
          float hr = acch[t][1][reg] + bhr;
          float hh = acch[t][2][reg] + bhh;
          float z = fsigmoid(xz + hz);
          float rr = fsigmoid(xr + hr);
          float hc = ftanh(xh + rr * hh);
          float* hp2 = H + (size_t)r * 128 + hcol;
          float hold = *hp2;
          *hp2 = z * hold + (1.f - z) * hc;
        }
      }
    }
  }
}

// ---------------- bf16 MFMA GEMM: C[M,Nc] = act(A[M,128] @ W[128,Nc] + bias) ----------------
template <int RELU>
__global__ __launch_bounds__(256) void gemm_bf16(
    const float* __restrict__ A, const float* __restrict__ W,
    const float* __restrict__ bias, float* __restrict__ C, int M, int Nc) {
  constexpr int LDA = 136;
  __shared__ __align__(16) u16 As[64 * LDA];
  __shared__ __align__(16) u16 Bs[64 * LDA];
  const int bm = blockIdx.x * 64, bn = blockIdx.y * 64;
  const int tid = threadIdx.x;
#pragma unroll
  for (int i = 0; i < 8; i++) {
    int l = tid + i * 256;
    int r = l >> 5, c4 = (l & 31) << 2;
    int gr = bm + r;
    float4 v = make_float4(0, 0, 0, 0);
    if (gr < M) v = *(const float4*)(A + (size_t)gr * 128 + c4);
    u16* p = As + r * LDA + c4;
    p[0] = f2bf(v.x); p[1] = f2bf(v.y); p[2] = f2bf(v.z); p[3] = f2bf(v.w);
  }
#pragma unroll
  for (int i = 0; i < 8; i++) {
    int l = tid + i * 256;
    int k = l >> 4, n4 = (l & 15) << 2;
    float4 v = *(const float4*)(W + (size_t)k * Nc + bn + n4);
    Bs[(n4 + 0) * LDA + k] = f2bf(v.x);
    Bs[(n4 + 1) * LDA + k] = f2bf(v.y);
    Bs[(n4 + 2) * LDA + k] = f2bf(v.z);
    Bs[(n4 + 3) * LDA + k] = f2bf(v.w);
  }
  __syncthreads();
  const int wv = tid >> 6, lane = tid & 63;
  const int lrow = lane & 15, quad = lane >> 4;
  floatx4 acc[4] = {{0,0,0,0},{0,0,0,0},{0,0,0,0},{0,0,0,0}};
  const u16* arow = As + (wv * 16 + lrow) * LDA + quad * 8;
#pragma unroll
  for (int ks = 0; ks < 4; ks++) {
    bf16x8 af = *(const bf16x8*)(arow + ks * 32);
#pragma unroll
    for (int nt = 0; nt < 4; nt++) {
      bf16x8 bfr = *(const bf16x8*)(Bs + (nt * 16 + lrow) * LDA + quad * 8 + ks * 32);
      acc[nt] = __builtin_amdgcn_mfma_f32_16x16x32_bf16(af, bfr, acc[nt], 0, 0, 0);
    }
  }
#pragma unroll
  for (int nt = 0; nt < 4; nt++) {
    int col = bn + nt * 16 + lrow;
    float bv = bias ? bias[col] : 0.f;
#pragma unroll
    for (int reg = 0; reg < 4; reg++) {
      int gr = bm + wv * 16 + quad * 4 + reg;
      if (gr < M) {
        float v = acc[nt][reg] + bv;
        if (RELU) v = fmaxf(v, 0.f);
        C[(size_t)gr * Nc + col] = v;
      }
    }
  }
}

// ---------------- fused final layer: logits + softmax ----------------
__global__ void k_readout(const float* __restrict__ h2, const float* __restrict__ W3,
                          const float* __restrict__ b3, float* __restrict__ out) {
  __shared__ float w[64 * 15];
  __shared__ float b[15];
  for (int l = threadIdx.x; l < 960; l += blockDim.x) w[l] = W3[l];
  if (threadIdx.x < 15) b[threadIdx.x] = b3[threadIdx.x];
  __syncthreads();
  int r = blockIdx.x * blockDim.x + threadIdx.x;
  if (r >= N_CONN) return;
  float hv[64];
  const float4* hp = (const float4*)(h2 + (size_t)r * 64);
#pragma unroll
  for (int i = 0; i < 16; i++) {
    float4 v = hp[i];
    hv[4 * i] = v.x; hv[4 * i + 1] = v.y; hv[4 * i + 2] = v.z; hv[4 * i + 3] = v.w;
  }
  float lg[15];
#pragma unroll
  for (int c = 0; c < 15; c++) lg[c] = b[c];
  for (int k = 0; k < 64; k++) {
    float hk = hv[k];
#pragma unroll
    for (int c = 0; c < 15; c++) lg[c] += hk * w[k * 15 + c];
  }
  float m = lg[0];
#pragma unroll
  for (int c = 1; c < 15; c++) m = fmaxf(m, lg[c]);
  float ssum = 0.f;
#pragma unroll
  for (int c = 0; c < 15; c++) { lg[c] = __expf(lg[c] - m); ssum += lg[c]; }
  float inv = 1.f / ssum;
#pragma unroll
  for (int c = 0; c < 15; c++) out[(size_t)r * 15 + c] = lg[c] * inv;
}

// ---------------- launch ----------------
extern "C" void kernel_launch(void* const* d_in, const int* in_sizes, int n_in,
                              void* d_out, int out_size, void* d_ws, size_t ws_size,
                              hipStream_t stream) {
  const float* feat = (const float*)d_in[0];
  const int* src1 = (const int*)d_in[1];
  const int* dst1 = (const int*)d_in[2];
  const int* src2 = (const int*)d_in[3];
  const int* dst2 = (const int*)d_in[4];
  const float* Wm1 = (const float*)d_in[5];
  const float* bm1 = (const float*)d_in[6];
  const float* Wm2 = (const float*)d_in[7];
  const float* bm2 = (const float*)d_in[8];
  const float* gik = (const float*)d_in[9];
  const float* gir = (const float*)d_in[10];
  const float* gib = (const float*)d_in[11];
  const float* gck = (const float*)d_in[12];
  const float* gcr = (const float*)d_in[13];
  const float* gcb = (const float*)d_in[14];
  const float* Wr1 = (const float*)d_in[15];
  const float* br1 = (const float*)d_in[16];
  const float* Wr2 = (const float*)d_in[17];
  const float* br2 = (const float*)d_in[18];
  const float* Wr3 = (const float*)d_in[19];
  const float* br3 = (const float*)d_in[20];
  float* out = (float*)d_out;

  // ---- workspace layout ----
  float* ws = (float*)d_ws;
  size_t o = 0;
  float* ip_state = ws + o;   o += (size_t)N_IP * D;
  float* conn_state = ws + o; o += (size_t)N_CONN * D;
  float* sum1 = ws + o;       o += (size_t)N_CONN * D;
  float* sum2 = ws + o;       o += (size_t)N_IP * D;
  float* R = ws + o;          o += (size_t)19200000;
  float* P1 = R;                          // msg1: ip rows (N_IP*D)
  float* P2 = R;                          // msg2: conn rows (N_CONN*D)
  float* h1 = R;                          // readout
  float* h2 = R + (size_t)N_CONN * D;
  u16* wb = (u16*)(ws + o); o += 98304;   // 4 x 49152 u16 GRU weights
  u16* gikb = wb;
  u16* girb = wb + 49152;
  u16* gckb = wb + 2 * 49152;
  u16* gcrb = wb + 3 * 49152;
  u16* wmb = (u16*)(ws + o); o += 8192;   // 2 x 16384 u16 message bottom weights
  u16* wm1b = wmb;
  u16* wm2b = wmb + 16384;
  int* ip = (int*)(ws + o);
  int* cnt1 = ip;  ip += N_CONN;
  int* cnt2 = ip;  ip += N_IP;
  int* off1 = ip;  ip += N_CONN;
  int* off2 = ip;  ip += N_IP;
  int* cur1 = ip;  ip += N_CONN;
  int* cur2 = ip;  ip += N_IP;
  int* srcs1 = ip; ip += NE;
  int* srcs2 = ip; ip += NE;
  int* bsum1 = ip; ip += 256;
  int* bsum2 = ip; ip += 256;

  const int BT = 256;

  // ---- init states + weight prep ----
  k_fill1<<<(N_IP * D / 4 + BT - 1) / BT, BT, 0, stream>>>(ip_state, N_IP * D / 4);
  k_init_conn<<<(N_CONN * D + BT - 1) / BT, BT, 0, stream>>>(conn_state, feat);
  k_prep_w<<<(384 * 128 + BT - 1) / BT, BT, 0, stream>>>(gik, gikb);
  k_prep_w<<<(384 * 128 + BT - 1) / BT, BT, 0, stream>>>(gir, girb);
  k_prep_w<<<(384 * 128 + BT - 1) / BT, BT, 0, stream>>>(gck, gckb);
  k_prep_w<<<(384 * 128 + BT - 1) / BT, BT, 0, stream>>>(gcr, gcrb);
  k_prep_w128<<<(128 * 128 + BT - 1) / BT, BT, 0, stream>>>(Wm1, wm1b);
  k_prep_w128<<<(128 * 128 + BT - 1) / BT, BT, 0, stream>>>(Wm2, wm2b);

  // ---- build CSR ----
  hipMemsetAsync(cnt1, 0, (size_t)(N_CONN + N_IP) * sizeof(int), stream);
  k_count<<<(NE + BT - 1) / BT, BT, 0, stream>>>(dst1, dst2, cnt1, cnt2);
  const int nb1 = (N_CONN + 1023) / 1024, nb2 = (N_IP + 1023) / 1024;
  k_scan_part<<<nb1, 256, 0, stream>>>(cnt1, bsum1, N_CONN);
  k_scan_part<<<nb2, 256, 0, stream>>>(cnt2, bsum2, N_IP);
  k_scan_mid<<<1, 256, 0, stream>>>(bsum1, nb1);
  k_scan_mid<<<1, 256, 0, stream>>>(bsum2, nb2);
  k_scan_final<<<nb1, 256, 0, stream>>>(cnt1, bsum1, off1, N_CONN);
  k_scan_final<<<nb2, 256, 0, stream>>>(cnt2, bsum2, off2, N_IP);
  k_copyint<<<(N_CONN + N_IP + BT - 1) / BT, BT, 0, stream>>>(off1, cur1, N_CONN + N_IP);
  k_scatter<<<(NE + BT - 1) / BT, BT, 0, stream>>>(src1, dst1, src2, dst2,
                                                   cur1, cur2, srcs1, srcs2);

  dim3 gIP128((N_IP + 63) / 64, 2);
  dim3 gCN128((N_CONN + 63) / 64, 2);
  const int gQC = (N_CONN + 63) / 64;
  const int gQI = (N_IP + 63) / 64;

  for (int t = 0; t < T_ROUNDS; t++) {
    // message 1 (ip -> conn): P1 = ip_state @ Wm1_top; fused Q+gather over conn
    gemm_bf16<0><<<gIP128, 256, 0, stream>>>(ip_state, Wm1, nullptr, P1, N_IP, 128);
    k_qgather<<<gQC, 256, 0, stream>>>(conn_state, wm1b, bm1, P1,
                                       srcs1, off1, cnt1, sum1, N_CONN);
    // message 2 (conn -> ip): P2 = conn_state @ Wm2_top; fused Q+gather over ip
    gemm_bf16<0><<<gCN128, 256, 0, stream>>>(conn_state, Wm2, nullptr, P2, N_CONN, 128);
    k_qgather<<<gQI, 256, 0, stream>>>(ip_state, wm2b, bm2, P2,
                                       srcs2, off2, cnt2, sum2, N_IP);
    // fused GRUs (in-place state update)
    k_gru_fused<<<gQI, 256, 0, stream>>>(sum2, gikb, girb, gib, ip_state, N_IP);
    k_gru_fused<<<gQC, 256, 0, stream>>>(sum1, gckb, gcrb, gcb, conn_state, N_CONN);
  }

  // readout
  gemm_bf16<1><<<gCN128, 256, 0, stream>>>(conn_state, Wr1, br1, h1, N_CONN, 128);
  dim3 gH2((N_CONN + 63) / 64, 1);
  gemm_bf16<1><<<gH2, 256, 0, stream>>>(h1, Wr2, br2, h2, N_CONN, 64);
  k_readout<<<(N_CONN + BT - 1) / BT, BT, 0, stream>>>(h2, Wr3, br3, out);
}

// Round 6
// 796.450 us; speedup vs baseline: 1.5848x; 1.5848x over previous
//
#include <hip/hip_runtime.h>
#include <math.h>

#define D 128
#define NF 10
#define N_IP 20000
#define N_CONN 100000
#define NE 200000
#define T_ROUNDS 3

typedef unsigned short u16;
using bf16x8 = __attribute__((ext_vector_type(8))) short;
using floatx4 = __attribute__((ext_vector_type(4))) float;

__device__ inline u16 f2bf(float f) {
  union { float f; unsigned u; } v; v.f = f;
  unsigned u = v.u;
  return (u16)((u + 0x7fffu + ((u >> 16) & 1u)) >> 16);  // RNE
}

__device__ inline bf16x8 pack8(float4 a, float4 b) {
  bf16x8 r;
  r[0] = (short)f2bf(a.x); r[1] = (short)f2bf(a.y);
  r[2] = (short)f2bf(a.z); r[3] = (short)f2bf(a.w);
  r[4] = (short)f2bf(b.x); r[5] = (short)f2bf(b.y);
  r[6] = (short)f2bf(b.z); r[7] = (short)f2bf(b.w);
  return r;
}

__device__ inline float fsigmoid(float s) { return 1.f / (1.f + __expf(-s)); }
__device__ inline float ftanh(float a) {
  a = fminf(fmaxf(a, -15.f), 15.f);
  float e = __expf(2.f * a);
  return (e - 1.f) / (e + 1.f);
}

// ---------------- utility kernels ----------------

__global__ void k_fill1(float* p, int n4) {
  int i = blockIdx.x * blockDim.x + threadIdx.x;
  if (i < n4) ((float4*)p)[i] = make_float4(1.f, 1.f, 1.f, 1.f);
}

__global__ void k_init_conn(float* __restrict__ cs, const float* __restrict__ feat) {
  int i = blockIdx.x * blockDim.x + threadIdx.x;
  if (i >= N_CONN * D) return;
  int r = i >> 7, j = i & 127;
  cs[i] = (j < NF) ? feat[r * NF + j] : 0.f;
}

__global__ void k_count(const int* __restrict__ d1, const int* __restrict__ d2,
                        int* __restrict__ c1, int* __restrict__ c2) {
  int e = blockIdx.x * blockDim.x + threadIdx.x;
  if (e >= NE) return;
  atomicAdd(&c1[d1[e]], 1);
  atomicAdd(&c2[d2[e]], 1);
}

// GRU weights: 128x384 fp32 -> [col][k] 384x128 bf16
__global__ void k_prep_w(const float* __restrict__ W, u16* __restrict__ Wb) {
  int i = blockIdx.x * blockDim.x + threadIdx.x;
  if (i >= 384 * 128) return;
  int col = i >> 7, k = i & 127;
  Wb[i] = f2bf(W[k * 384 + col]);
}

// message weight bottom half: W[128..255][0..127] fp32 -> [col][k] 128x128 bf16
__global__ void k_prep_w128(const float* __restrict__ W, u16* __restrict__ Wb) {
  int i = blockIdx.x * blockDim.x + threadIdx.x;
  if (i >= 128 * 128) return;
  int col = i >> 7, k = i & 127;
  Wb[i] = f2bf(W[(128 + k) * 128 + col]);
}

// ---------------- parallel 3-pass exclusive scan ----------------
__global__ void k_scan_part(const int* __restrict__ cnt, int* __restrict__ bsum, int n) {
  int t = threadIdx.x;  // 256
  int base = blockIdx.x * 1024 + t * 4;
  int s = 0;
#pragma unroll
  for (int i = 0; i < 4; i++) { int j = base + i; if (j < n) s += cnt[j]; }
  for (int d = 32; d > 0; d >>= 1) s += __shfl_xor(s, d, 64);
  __shared__ int wred[4];
  int lane = t & 63, wv = t >> 6;
  if (lane == 0) wred[wv] = s;
  __syncthreads();
  if (t == 0) bsum[blockIdx.x] = wred[0] + wred[1] + wred[2] + wred[3];
}

__global__ void k_scan_mid(int* __restrict__ bsum, int m) {
  int t = threadIdx.x;
  int v = (t < m) ? bsum[t] : 0;
  int lane = t & 63, wv = t >> 6;
  int x = v;
  for (int d = 1; d < 64; d <<= 1) { int y = __shfl_up(x, d, 64); if (lane >= d) x += y; }
  __shared__ int wsum[4];
  if (lane == 63) wsum[wv] = x;
  __syncthreads();
  int add = 0;
  for (int i = 0; i < wv; i++) add += wsum[i];
  int ex = add + x - v;
  if (t < m) bsum[t] = ex;
}

__global__ void k_scan_final(const int* __restrict__ cnt, const int* __restrict__ bsum,
                             int* __restrict__ off, int n) {
  int t = threadIdx.x;
  int base = blockIdx.x * 1024 + t * 4;
  int vals[4]; int s = 0;
#pragma unroll
  for (int i = 0; i < 4; i++) {
    int j = base + i;
    vals[i] = (j < n) ? cnt[j] : 0;
    s += vals[i];
  }
  int lane = t & 63, wv = t >> 6;
  int x = s;
  for (int d = 1; d < 64; d <<= 1) { int y = __shfl_up(x, d, 64); if (lane >= d) x += y; }
  __shared__ int wsum[4];
  if (lane == 63) wsum[wv] = x;
  __syncthreads();
  int add = 0;
  for (int i = 0; i < wv; i++) add += wsum[i];
  int run = add + x - s + bsum[blockIdx.x];
#pragma unroll
  for (int i = 0; i < 4; i++) {
    int j = base + i;
    if (j < n) off[j] = run;
    run += vals[i];
  }
}

__global__ void k_copyint(const int* __restrict__ a, int* __restrict__ b, int n) {
  int i = blockIdx.x * blockDim.x + threadIdx.x;
  if (i < n) b[i] = a[i];
}

__global__ void k_scatter(const int* __restrict__ s1, const int* __restrict__ d1,
                          const int* __restrict__ s2, const int* __restrict__ d2,
                          int* __restrict__ cur1, int* __restrict__ cur2,
                          int* __restrict__ o1, int* __restrict__ o2) {
  int e = blockIdx.x * blockDim.x + threadIdx.x;
  if (e >= NE) return;
  int p1 = atomicAdd(&cur1[d1[e]], 1);
  o1[p1] = s1[e];
  int p2 = atomicAdd(&cur2[d2[e]], 1);
  o2[p2] = s2[e];
}

// ---------------- merged P-GEMM: P = state @ Wtop (no bias, no act) ----------------
// grid.x = tiles1 + tiles2 (block picks side), grid.y = n-half (Nc=128)
__global__ __launch_bounds__(256) void k_gemmP(
    const float* __restrict__ A1, const float* __restrict__ W1, float* __restrict__ C1,
    int M1, int tiles1,
    const float* __restrict__ A2, const float* __restrict__ W2, float* __restrict__ C2,
    int M2) {
  constexpr int LDA = 136;
  __shared__ __align__(16) u16 As[64 * LDA];
  __shared__ __align__(16) u16 Bs[64 * LDA];
  const float* A; const float* W; float* C; int M, bm;
  if ((int)blockIdx.x < tiles1) { A = A1; W = W1; C = C1; M = M1; bm = blockIdx.x * 64; }
  else { A = A2; W = W2; C = C2; M = M2; bm = (blockIdx.x - tiles1) * 64; }
  const int bn = blockIdx.y * 64;
  const int tid = threadIdx.x;
#pragma unroll
  for (int i = 0; i < 8; i++) {
    int l = tid + i * 256;
    int r = l >> 5, c4 = (l & 31) << 2;
    int gr = bm + r;
    float4 v = make_float4(0, 0, 0, 0);
    if (gr < M) v = *(const float4*)(A + (size_t)gr * 128 + c4);
    u16* p = As + r * LDA + c4;
    p[0] = f2bf(v.x); p[1] = f2bf(v.y); p[2] = f2bf(v.z); p[3] = f2bf(v.w);
  }
#pragma unroll
  for (int i = 0; i < 8; i++) {
    int l = tid + i * 256;
    int k = l >> 4, n4 = (l & 15) << 2;
    float4 v = *(const float4*)(W + (size_t)k * 128 + bn + n4);
    Bs[(n4 + 0) * LDA + k] = f2bf(v.x);
    Bs[(n4 + 1) * LDA + k] = f2bf(v.y);
    Bs[(n4 + 2) * LDA + k] = f2bf(v.z);
    Bs[(n4 + 3) * LDA + k] = f2bf(v.w);
  }
  __syncthreads();
  const int wv = tid >> 6, lane = tid & 63;
  const int lrow = lane & 15, quad = lane >> 4;
  floatx4 acc[4] = {{0,0,0,0},{0,0,0,0},{0,0,0,0},{0,0,0,0}};
  const u16* arow = As + (wv * 16 + lrow) * LDA + quad * 8;
#pragma unroll
  for (int ks = 0; ks < 4; ks++) {
    bf16x8 af = *(const bf16x8*)(arow + ks * 32);
#pragma unroll
    for (int nt = 0; nt < 4; nt++) {
      bf16x8 bfr = *(const bf16x8*)(Bs + (nt * 16 + lrow) * LDA + quad * 8 + ks * 32);
      acc[nt] = __builtin_amdgcn_mfma_f32_16x16x32_bf16(af, bfr, acc[nt], 0, 0, 0);
    }
  }
#pragma unroll
  for (int nt = 0; nt < 4; nt++) {
    int col = bn + nt * 16 + lrow;
#pragma unroll
    for (int reg = 0; reg < 4; reg++) {
      int gr = bm + wv * 16 + quad * 4 + reg;
      if (gr < M) C[(size_t)gr * 128 + col] = acc[nt][reg];
    }
  }
}

// ---------------- merged fused Q-GEMM + gather-mean ----------------
__global__ __launch_bounds__(256) void k_qgather(
    const float* __restrict__ S1, const u16* __restrict__ Wb1, const float* __restrict__ bias1,
    const float* __restrict__ P1g, const int* __restrict__ srcs1g,
    const int* __restrict__ off1g, const int* __restrict__ cnt1g,
    float* __restrict__ out1, int n1, int tiles1,
    const float* __restrict__ S2, const u16* __restrict__ Wb2, const float* __restrict__ bias2,
    const float* __restrict__ P2g, const int* __restrict__ srcs2g,
    const int* __restrict__ off2g, const int* __restrict__ cnt2g,
    float* __restrict__ out2, int n2) {
  __shared__ __align__(16) char smem[64 * 132 * 4];  // 33792 B
  u16* Wls = (u16*)smem;
  float* Qls = (float*)smem;
  const float* S; const u16* Wb; const float* bias; const float* P;
  const int* srcs; const int* off; const int* cnt; float* outm; int nnodes, bm;
  if ((int)blockIdx.x < tiles1) {
    S = S1; Wb = Wb1; bias = bias1; P = P1g; srcs = srcs1g; off = off1g; cnt = cnt1g;
    outm = out1; nnodes = n1; bm = blockIdx.x * 64;
  } else {
    S = S2; Wb = Wb2; bias = bias2; P = P2g; srcs = srcs2g; off = off2g; cnt = cnt2g;
    outm = out2; nnodes = n2; bm = (blockIdx.x - tiles1) * 64;
  }
  const int tid = threadIdx.x, wv = tid >> 6, lane = tid & 63;
  const int lrow = lane & 15, quad = lane >> 4;

  // stage W (coalesced 16B, swizzle granule ^= col&15)
#pragma unroll
  for (int i = 0; i < 8; i++) {
    int task = i * 256 + tid;
    int col = task >> 4, gr = task & 15;
    uint4 v = *(const uint4*)(Wb + (size_t)col * 128 + gr * 8);
    *(uint4*)(Wls + (size_t)col * 128 + ((gr ^ (col & 15)) * 8)) = v;
  }
  const int arow = bm + wv * 16 + lrow;
  const bool arv = arow < nnodes;
  bf16x8 ax[4];
  {
    const float* xp = S + (size_t)arow * 128 + quad * 8;
#pragma unroll
    for (int ks = 0; ks < 4; ks++) {
      float4 a0 = make_float4(0, 0, 0, 0), a1 = a0;
      if (arv) {
        a0 = *(const float4*)(xp + ks * 32);
        a1 = *(const float4*)(xp + ks * 32 + 4);
      }
      ax[ks] = pack8(a0, a1);
    }
  }
  __syncthreads();
  floatx4 acc[8];
#pragma unroll
  for (int ct = 0; ct < 8; ct++) acc[ct] = {0.f, 0.f, 0.f, 0.f};
#pragma unroll
  for (int ks = 0; ks < 4; ks++) {
#pragma unroll
    for (int ct = 0; ct < 8; ct++) {
      int col = ct * 16 + lrow;
      bf16x8 b = *(const bf16x8*)(Wls + (size_t)col * 128 + (((4 * ks + quad) ^ lrow) * 8));
      acc[ct] = __builtin_amdgcn_mfma_f32_16x16x32_bf16(ax[ks], b, acc[ct], 0, 0, 0);
    }
  }
  __syncthreads();  // all W reads done; reuse smem as Q
#pragma unroll
  for (int ct = 0; ct < 8; ct++) {
    int col = ct * 16 + lrow;
    float bv = bias[col];
#pragma unroll
    for (int reg = 0; reg < 4; reg++) {
      int lr = wv * 16 + quad * 4 + reg;
      Qls[(size_t)lr * 132 + col] = acc[ct][reg] + bv;
    }
  }
  __syncthreads();
#pragma unroll
  for (int it = 0; it < 8; it++) {
    int task = it * 256 + tid;
    int nl = task >> 5, c4 = (task & 31) << 2;
    int node = bm + nl;
    if (node >= nnodes) continue;
    float* qp = Qls + (size_t)nl * 132 + c4;
    float qx = qp[0], qy = qp[1], qz = qp[2], qw = qp[3];
    float ax2 = 0.f, ay = 0.f, az = 0.f, aw = 0.f;
    int o = off[node], n = cnt[node];
    int i = 0;
    for (; i + 4 <= n; i += 4) {
      int s0 = srcs[o + i], s1 = srcs[o + i + 1], s2 = srcs[o + i + 2], s3 = srcs[o + i + 3];
      float4 p0 = *(const float4*)(P + (size_t)s0 * D + c4);
      float4 p1 = *(const float4*)(P + (size_t)s1 * D + c4);
      float4 p2 = *(const float4*)(P + (size_t)s2 * D + c4);
      float4 p3 = *(const float4*)(P + (size_t)s3 * D + c4);
      ax2 += fmaxf(p0.x + qx, 0.f) + fmaxf(p1.x + qx, 0.f) + fmaxf(p2.x + qx, 0.f) + fmaxf(p3.x + qx, 0.f);
      ay += fmaxf(p0.y + qy, 0.f) + fmaxf(p1.y + qy, 0.f) + fmaxf(p2.y + qy, 0.f) + fmaxf(p3.y + qy, 0.f);
      az += fmaxf(p0.z + qz, 0.f) + fmaxf(p1.z + qz, 0.f) + fmaxf(p2.z + qz, 0.f) + fmaxf(p3.z + qz, 0.f);
      aw += fmaxf(p0.w + qw, 0.f) + fmaxf(p1.w + qw, 0.f) + fmaxf(p2.w + qw, 0.f) + fmaxf(p3.w + qw, 0.f);
    }
    for (; i + 2 <= n; i += 2) {
      int s0 = srcs[o + i], s1 = srcs[o + i + 1];
      float4 p0 = *(const float4*)(P + (size_t)s0 * D + c4);
      float4 p1 = *(const float4*)(P + (size_t)s1 * D + c4);
      ax2 += fmaxf(p0.x + qx, 0.f) + fmaxf(p1.x + qx, 0.f);
      ay += fmaxf(p0.y + qy, 0.f) + fmaxf(p1.y + qy, 0.f);
      az += fmaxf(p0.z + qz, 0.f) + fmaxf(p1.z + qz, 0.f);
      aw += fmaxf(p0.w + qw, 0.f) + fmaxf(p1.w + qw, 0.f);
    }
    if (i < n) {
      int s0 = srcs[o + i];
      float4 p0 = *(const float4*)(P + (size_t)s0 * D + c4);
      ax2 += fmaxf(p0.x + qx, 0.f);
      ay += fmaxf(p0.y + qy, 0.f);
      az += fmaxf(p0.z + qz, 0.f);
      aw += fmaxf(p0.w + qw, 0.f);
    }
    float inv = 1.f / fmaxf((float)n, 1.f);
    *(float4*)(outm + (size_t)node * D + c4) =
        make_float4(ax2 * inv, ay * inv, az * inv, aw * inv);
  }
}

// ---------------- merged fused GRU v4: 128 rows/block, swizzled LDS, no reg-prefetch ----------------
// Each wave: 2 row-tiles of 16; B-frag LDS reads shared across both tiles.
__global__ __launch_bounds__(256, 2) void k_gru_fused(
    const float* __restrict__ X1, const u16* __restrict__ Wx1, const u16* __restrict__ Wh1,
    const float* __restrict__ b1, float* __restrict__ H1, int r1, int tiles1,
    const float* __restrict__ X2, const u16* __restrict__ Wx2, const u16* __restrict__ Wh2,
    const float* __restrict__ b2, float* __restrict__ H2, int r2) {
  __shared__ __align__(16) u16 Ls[6 * 32 * 128];  // 49152 B
  const float* X; const u16* Wxb; const u16* Whb; const float* bias; float* H;
  int rows, bm;
  if ((int)blockIdx.x < tiles1) {
    X = X1; Wxb = Wx1; Whb = Wh1; bias = b1; H = H1; rows = r1; bm = blockIdx.x * 128;
  } else {
    X = X2; Wxb = Wx2; Whb = Wh2; bias = b2; H = H2; rows = r2;
    bm = (blockIdx.x - tiles1) * 128;
  }
  const int tid = threadIdx.x, wv = tid >> 6, lane = tid & 63;
  const int lrow = lane & 15, quad = lane >> 4;
  bf16x8 ax[2][4], ah[2][4];
#pragma unroll
  for (int tile = 0; tile < 2; tile++) {
    int arow = bm + tile * 64 + wv * 16 + lrow;
    bool arv = arow < rows;
    const float* xp = X + (size_t)arow * 128 + quad * 8;
    const float* hp = H + (size_t)arow * 128 + quad * 8;
#pragma unroll
    for (int ks = 0; ks < 4; ks++) {
      float4 a0 = make_float4(0, 0, 0, 0), a1 = a0, b0 = a0, b1v = a0;
      if (arv) {
        a0 = *(const float4*)(xp + ks * 32);
        a1 = *(const float4*)(xp + ks * 32 + 4);
        b0 = *(const float4*)(hp + ks * 32);
        b1v = *(const float4*)(hp + ks * 32 + 4);
      }
      ax[tile][ks] = pack8(a0, a1);
      ah[tile][ks] = pack8(b0, b1v);
    }
  }
  for (int ch = 0; ch < 4; ch++) {
    __syncthreads();  // prev chunk's LDS readers done
    // stage 48KB (3072 uint4 tasks): two passes of 6, regs short-lived
#pragma unroll
    for (int p = 0; p < 2; p++) {
      uint4 v[6];
#pragma unroll
      for (int j = 0; j < 6; j++) {
        int task = (p * 6 + j) * 256 + tid;
        int seg = task >> 9, rem = task & 511;
        int col = rem >> 4, g = rem & 15;
        const u16* gsrc = (seg < 3 ? Wxb : Whb) +
                          (size_t)((seg < 3 ? seg : seg - 3) * 128 + ch * 32 + col) * 128 + g * 8;
        v[j] = *(const uint4*)gsrc;
      }
#pragma unroll
      for (int j = 0; j < 6; j++) {
        int task = (p * 6 + j) * 256 + tid;
        int seg = task >> 9, rem = task & 511;
        int col = rem >> 4, g = rem & 15;
        *(uint4*)(Ls + (size_t)(seg * 32 + col) * 128 + ((g ^ (col & 15)) * 8)) = v[j];
      }
    }
    __syncthreads();
    floatx4 acc[2][2][3][2];  // tile, t, gate, x/h -> 96 VGPRs
#pragma unroll
    for (int tile = 0; tile < 2; tile++)
#pragma unroll
      for (int t = 0; t < 2; t++)
#pragma unroll
        for (int g = 0; g < 3; g++) {
          acc[tile][t][g][0] = {0.f, 0.f, 0.f, 0.f};
          acc[tile][t][g][1] = {0.f, 0.f, 0.f, 0.f};
        }
#pragma unroll
    for (int ks = 0; ks < 4; ks++) {
      int posu = ((4 * ks + quad) ^ lrow) * 8;
#pragma unroll
      for (int t = 0; t < 2; t++) {
        int cIdx = t * 16 + lrow;
#pragma unroll
        for (int g = 0; g < 3; g++) {
          bf16x8 bx = *(const bf16x8*)(Ls + (size_t)(g * 32 + cIdx) * 128 + posu);
          bf16x8 bh = *(const bf16x8*)(Ls + (size_t)((3 + g) * 32 + cIdx) * 128 + posu);
          acc[0][t][g][0] = __builtin_amdgcn_mfma_f32_16x16x32_bf16(ax[0][ks], bx, acc[0][t][g][0], 0, 0, 0);
          acc[0][t][g][1] = __builtin_amdgcn_mfma_f32_16x16x32_bf16(ah[0][ks], bh, acc[0][t][g][1], 0, 0, 0);
          acc[1][t][g][0] = __builtin_amdgcn_mfma_f32_16x16x32_bf16(ax[1][ks], bx, acc[1][t][g][0], 0, 0, 0);
          acc[1][t][g][1] = __builtin_amdgcn_mfma_f32_16x16x32_bf16(ah[1][ks], bh, acc[1][t][g][1], 0, 0, 0);
        }
      }
    }
#pragma unroll
    for (int tile = 0; tile < 2; tile++) {
#pragma unroll
      for (int t = 0; t < 2; t++) {
        int hcol = ch * 32 + t * 16 + lrow;
        float bxz = bias[hcol];
        float bxr = bias[128 + hcol];
        float bxh = bias[256 + hcol];
        float bhz = bias[384 + hcol];
        float bhr = bias[384 + 128 + hcol];
        float bhh = bias[384 + 256 + hcol];
#pragma unroll
        for (int reg = 0; reg < 4; reg++) {
          int r = bm + tile * 64 + wv * 16 + quad * 4 + reg;
          if (r < rows) {
            float xz = acc[tile][t][0][0][reg] + bxz;
            float xr = acc[tile][t][1][0][reg] + bxr;
            float xh = acc[tile][t][2][0][reg] + bxh;
            float hz = acc[tile][t][0][1][reg] + bhz;
            float hr = acc[tile][t][1][1][reg] + bhr;
            float hh = acc[tile][t][2][1][reg] + bhh;
            float z = fsigmoid(xz + hz);
            float rr = fsigmoid(xr + hr);
            float hc = ftanh(xh + rr * hh);
            float* hp2 = H + (size_t)r * 128 + hcol;
            float hold = *hp2;
            *hp2 = z * hold + (1.f - z) * hc;
          }
        }
      }
    }
  }
}

// ---------------- generic bf16 MFMA GEMM (readout): C = act(A@W + bias) ----------------
template <int RELU>
__global__ __launch_bounds__(256) void gemm_bf16(
    const float* __restrict__ A, const float* __restrict__ W,
    const float* __restrict__ bias, float* __restrict__ C, int M, int Nc) {
  constexpr int LDA = 136;
  __shared__ __align__(16) u16 As[64 * LDA];
  __shared__ __align__(16) u16 Bs[64 * LDA];
  const int bm = blockIdx.x * 64, bn = blockIdx.y * 64;
  const int tid = threadIdx.x;
#pragma unroll
  for (int i = 0; i < 8; i++) {
    int l = tid + i * 256;
    int r = l >> 5, c4 = (l & 31) << 2;
    int gr = bm + r;
    float4 v = make_float4(0, 0, 0, 0);
    if (gr < M) v = *(const float4*)(A + (size_t)gr * 128 + c4);
    u16* p = As + r * LDA + c4;
    p[0] = f2bf(v.x); p[1] = f2bf(v.y); p[2] = f2bf(v.z); p[3] = f2bf(v.w);
  }
#pragma unroll
  for (int i = 0; i < 8; i++) {
    int l = tid + i * 256;
    int k = l >> 4, n4 = (l & 15) << 2;
    float4 v = *(const float4*)(W + (size_t)k * Nc + bn + n4);
    Bs[(n4 + 0) * LDA + k] = f2bf(v.x);
    Bs[(n4 + 1) * LDA + k] = f2bf(v.y);
    Bs[(n4 + 2) * LDA + k] = f2bf(v.z);
    Bs[(n4 + 3) * LDA + k] = f2bf(v.w);
  }
  __syncthreads();
  const int wv = tid >> 6, lane = tid & 63;
  const int lrow = lane & 15, quad = lane >> 4;
  floatx4 acc[4] = {{0,0,0,0},{0,0,0,0},{0,0,0,0},{0,0,0,0}};
  const u16* arow = As + (wv * 16 + lrow) * LDA + quad * 8;
#pragma unroll
  for (int ks = 0; ks < 4; ks++) {
    bf16x8 af = *(const bf16x8*)(arow + ks * 32);
#pragma unroll
    for (int nt = 0; nt < 4; nt++) {
      bf16x8 bfr = *(const bf16x8*)(Bs + (nt * 16 + lrow) * LDA + quad * 8 + ks * 32);
      acc[nt] = __builtin_amdgcn_mfma_f32_16x16x32_bf16(af, bfr, acc[nt], 0, 0, 0);
    }
  }
#pragma unroll
  for (int nt = 0; nt < 4; nt++) {
    int col = bn + nt * 16 + lrow;
    float bv = bias ? bias[col] : 0.f;
#pragma unroll
    for (int reg = 0; reg < 4; reg++) {
      int gr = bm + wv * 16 + quad * 4 + reg;
      if (gr < M) {
        float v = acc[nt][reg] + bv;
        if (RELU) v = fmaxf(v, 0.f);
        C[(size_t)gr * Nc + col] = v;
      }
    }
  }
}

// ---------------- fused final layer: logits + softmax ----------------
__global__ void k_readout(const float* __restrict__ h2, const float* __restrict__ W3,
                          const float* __restrict__ b3, float* __restrict__ out) {
  __shared__ float w[64 * 15];
  __shared__ float b[15];
  for (int l = threadIdx.x; l < 960; l += blockDim.x) w[l] = W3[l];
  if (threadIdx.x < 15) b[threadIdx.x] = b3[threadIdx.x];
  __syncthreads();
  int r = blockIdx.x * blockDim.x + threadIdx.x;
  if (r >= N_CONN) return;
  float hv[64];
  const float4* hp = (const float4*)(h2 + (size_t)r * 64);
#pragma unroll
  for (int i = 0; i < 16; i++) {
    float4 v = hp[i];
    hv[4 * i] = v.x; hv[4 * i + 1] = v.y; hv[4 * i + 2] = v.z; hv[4 * i + 3] = v.w;
  }
  float lg[15];
#pragma unroll
  for (int c = 0; c < 15; c++) lg[c] = b[c];
  for (int k = 0; k < 64; k++) {
    float hk = hv[k];
#pragma unroll
    for (int c = 0; c < 15; c++) lg[c] += hk * w[k * 15 + c];
  }
  float m = lg[0];
#pragma unroll
  for (int c = 1; c < 15; c++) m = fmaxf(m, lg[c]);
  float ssum = 0.f;
#pragma unroll
  for (int c = 0; c < 15; c++) { lg[c] = __expf(lg[c] - m); ssum += lg[c]; }
  float inv = 1.f / ssum;
#pragma unroll
  for (int c = 0; c < 15; c++) out[(size_t)r * 15 + c] = lg[c] * inv;
}

// ---------------- launch ----------------
extern "C" void kernel_launch(void* const* d_in, const int* in_sizes, int n_in,
                              void* d_out, int out_size, void* d_ws, size_t ws_size,
                              hipStream_t stream) {
  const float* feat = (const float*)d_in[0];
  const int* src1 = (const int*)d_in[1];
  const int* dst1 = (const int*)d_in[2];
  const int* src2 = (const int*)d_in[3];
  const int* dst2 = (const int*)d_in[4];
  const float* Wm1 = (const float*)d_in[5];
  const float* bm1 = (const float*)d_in[6];
  const float* Wm2 = (const float*)d_in[7];
  const float* bm2 = (const float*)d_in[8];
  const float* gik = (const float*)d_in[9];
  const float* gir = (const float*)d_in[10];
  const float* gib = (const float*)d_in[11];
  const float* gck = (const float*)d_in[12];
  const float* gcr = (const float*)d_in[13];
  const float* gcb = (const float*)d_in[14];
  const float* Wr1 = (const float*)d_in[15];
  const float* br1 = (const float*)d_in[16];
  const float* Wr2 = (const float*)d_in[17];
  const float* br2 = (const float*)d_in[18];
  const float* Wr3 = (const float*)d_in[19];
  const float* br3 = (const float*)d_in[20];
  float* out = (float*)d_out;

  // ---- workspace layout ----
  float* ws = (float*)d_ws;
  size_t o = 0;
  float* ip_state = ws + o;   o += (size_t)N_IP * D;
  float* conn_state = ws + o; o += (size_t)N_CONN * D;
  float* sum1 = ws + o;       o += (size_t)N_CONN * D;
  float* sum2 = ws + o;       o += (size_t)N_IP * D;
  float* R = ws + o;          o += (size_t)19200000;
  float* P1 = R;                          // ip rows (N_IP*D)
  float* P2 = R + (size_t)N_IP * D;       // conn rows (N_CONN*D) — coexists with P1
  float* h1 = R;                          // readout overlay (after msg phase dead)
  float* h2 = R + (size_t)N_CONN * D;
  u16* wb = (u16*)(ws + o); o += 98304;   // 4 x 49152 u16 GRU weights
  u16* gikb = wb;
  u16* girb = wb + 49152;
  u16* gckb = wb + 2 * 49152;
  u16* gcrb = wb + 3 * 49152;
  u16* wmb = (u16*)(ws + o); o += 8192;   // 2 x 16384 u16 message bottom weights
  u16* wm1b = wmb;
  u16* wm2b = wmb + 16384;
  int* ip = (int*)(ws + o);
  int* cnt1 = ip;  ip += N_CONN;
  int* cnt2 = ip;  ip += N_IP;
  int* off1 = ip;  ip += N_CONN;
  int* off2 = ip;  ip += N_IP;
  int* cur1 = ip;  ip += N_CONN;
  int* cur2 = ip;  ip += N_IP;
  int* srcs1 = ip; ip += NE;
  int* srcs2 = ip; ip += NE;
  int* bsum1 = ip; ip += 256;
  int* bsum2 = ip; ip += 256;

  const int BT = 256;

  // ---- init states + weight prep ----
  k_fill1<<<(N_IP * D / 4 + BT - 1) / BT, BT, 0, stream>>>(ip_state, N_IP * D / 4);
  k_init_conn<<<(N_CONN * D + BT - 1) / BT, BT, 0, stream>>>(conn_state, feat);
  k_prep_w<<<(384 * 128 + BT - 1) / BT, BT, 0, stream>>>(gik, gikb);
  k_prep_w<<<(384 * 128 + BT - 1) / BT, BT, 0, stream>>>(gir, girb);
  k_prep_w<<<(384 * 128 + BT - 1) / BT, BT, 0, stream>>>(gck, gckb);
  k_prep_w<<<(384 * 128 + BT - 1) / BT, BT, 0, stream>>>(gcr, gcrb);
  k_prep_w128<<<(128 * 128 + BT - 1) / BT, BT, 0, stream>>>(Wm1, wm1b);
  k_prep_w128<<<(128 * 128 + BT - 1) / BT, BT, 0, stream>>>(Wm2, wm2b);

  // ---- build CSR ----
  hipMemsetAsync(cnt1, 0, (size_t)(N_CONN + N_IP) * sizeof(int), stream);
  k_count<<<(NE + BT - 1) / BT, BT, 0, stream>>>(dst1, dst2, cnt1, cnt2);
  const int nb1 = (N_CONN + 1023) / 1024, nb2 = (N_IP + 1023) / 1024;
  k_scan_part<<<nb1, 256, 0, stream>>>(cnt1, bsum1, N_CONN);
  k_scan_part<<<nb2, 256, 0, stream>>>(cnt2, bsum2, N_IP);
  k_scan_mid<<<1, 256, 0, stream>>>(bsum1, nb1);
  k_scan_mid<<<1, 256, 0, stream>>>(bsum2, nb2);
  k_scan_final<<<nb1, 256, 0, stream>>>(cnt1, bsum1, off1, N_CONN);
  k_scan_final<<<nb2, 256, 0, stream>>>(cnt2, bsum2, off2, N_IP);
  k_copyint<<<(N_CONN + N_IP + BT - 1) / BT, BT, 0, stream>>>(off1, cur1, N_CONN + N_IP);
  k_scatter<<<(NE + BT - 1) / BT, BT, 0, stream>>>(src1, dst1, src2, dst2,
                                                   cur1, cur2, srcs1, srcs2);

  const int t64ip = (N_IP + 63) / 64;       // 313
  const int t64cn = (N_CONN + 63) / 64;     // 1563
  const int t128ip = (N_IP + 127) / 128;    // 157
  const int t128cn = (N_CONN + 127) / 128;  // 782
  dim3 gGemmP(t64ip + t64cn, 2);
  dim3 gCN128(t64cn, 2);

  for (int t = 0; t < T_ROUNDS; t++) {
    // P1 = ip_state @ Wm1_top; P2 = conn_state @ Wm2_top (one dispatch)
    k_gemmP<<<gGemmP, 256, 0, stream>>>(ip_state, Wm1, P1, N_IP, t64ip,
                                        conn_state, Wm2, P2, N_CONN);
    // fused Q+gather for both directions (one dispatch)
    k_qgather<<<t64cn + t64ip, 256, 0, stream>>>(
        conn_state, wm1b, bm1, P1, srcs1, off1, cnt1, sum1, N_CONN, t64cn,
        ip_state, wm2b, bm2, P2, srcs2, off2, cnt2, sum2, N_IP);
    // fused GRUs for both node types (one dispatch, in-place state update)
    k_gru_fused<<<t128cn + t128ip, 256, 0, stream>>>(
        sum1, gckb, gcrb, gcb, conn_state, N_CONN, t128cn,
        sum2, gikb, girb, gib, ip_state, N_IP);
  }

  // readout
  gemm_bf16<1><<<gCN128, 256, 0, stream>>>(conn_state, Wr1, br1, h1, N_CONN, 128);
  dim3 gH2(t64cn, 1);
  gemm_bf16<1><<<gH2, 256, 0, stream>>>(h1, Wr2, br2, h2, N_CONN, 64);
  k_readout<<<(N_CONN + BT - 1) / BT, BT, 0, stream>>>(h2, Wr3, br3, out);
}

// Round 7
// 575.037 us; speedup vs baseline: 2.1950x; 1.3850x over previous
//
#include <hip/hip_runtime.h>
#include <math.h>

#define D 128
#define NF 10
#define N_IP 20000
#define N_CONN 100000
#define NE 200000
#define T_ROUNDS 3

typedef unsigned short u16;
using bf16x8 = __attribute__((ext_vector_type(8))) short;
using floatx4 = __attribute__((ext_vector_type(4))) float;

__device__ inline u16 f2bf(float f) {
  union { float f; unsigned u; } v; v.f = f;
  unsigned u = v.u;
  return (u16)((u + 0x7fffu + ((u >> 16) & 1u)) >> 16);  // RNE
}
__device__ inline float bf2f(u16 h) {
  union { unsigned u; float f; } v; v.u = ((unsigned)h) << 16; return v.f;
}

__device__ inline float fsigmoid(float s) { return 1.f / (1.f + __expf(-s)); }
__device__ inline float ftanh(float a) {
  a = fminf(fmaxf(a, -15.f), 15.f);
  float e = __expf(2.f * a);
  return (e - 1.f) / (e + 1.f);
}

// ---------------- init / prep ----------------

__global__ void k_fill_bf1(unsigned* p, int n) {  // bf16(1.0) pairs
  int i = blockIdx.x * blockDim.x + threadIdx.x;
  if (i < n) p[i] = 0x3F803F80u;
}

__global__ void k_init_conn_bf(u16* __restrict__ cs, const float* __restrict__ feat) {
  int i = blockIdx.x * blockDim.x + threadIdx.x;  // N_CONN*128
  if (i >= N_CONN * D) return;
  int r = i >> 7, j = i & 127;
  cs[i] = (j < NF) ? f2bf(feat[r * NF + j]) : (u16)0;
}

__global__ void k_count(const int* __restrict__ d1, const int* __restrict__ d2,
                        int* __restrict__ c1, int* __restrict__ c2) {
  int e = blockIdx.x * blockDim.x + threadIdx.x;
  if (e >= NE) return;
  atomicAdd(&c1[d1[e]], 1);
  atomicAdd(&c2[d2[e]], 1);
}

// GRU weights: 128x384 fp32 -> [col][k] 384x128 bf16
__global__ void k_prep_w(const float* __restrict__ W, u16* __restrict__ Wb) {
  int i = blockIdx.x * blockDim.x + threadIdx.x;
  if (i >= 384 * 128) return;
  int col = i >> 7, k = i & 127;
  Wb[i] = f2bf(W[k * 384 + col]);
}
// 128x128 fp32 block (rows k0..k0+127) of a [*,128] matrix -> [col][k] bf16
__global__ void k_prep_w128(const float* __restrict__ W, u16* __restrict__ Wb, int k0) {
  int i = blockIdx.x * blockDim.x + threadIdx.x;
  if (i >= 128 * 128) return;
  int col = i >> 7, k = i & 127;
  Wb[i] = f2bf(W[(k0 + k) * 128 + col]);
}
// Wr2 128x64 fp32 -> [col][k] 64x128 bf16
__global__ void k_prep_wr2(const float* __restrict__ W, u16* __restrict__ Wb) {
  int i = blockIdx.x * blockDim.x + threadIdx.x;
  if (i >= 64 * 128) return;
  int col = i >> 7, k = i & 127;
  Wb[i] = f2bf(W[k * 64 + col]);
}

// ---------------- parallel 3-pass exclusive scan ----------------
__global__ void k_scan_part(const int* __restrict__ cnt, int* __restrict__ bsum, int n) {
  int t = threadIdx.x;
  int base = blockIdx.x * 1024 + t * 4;
  int s = 0;
#pragma unroll
  for (int i = 0; i < 4; i++) { int j = base + i; if (j < n) s += cnt[j]; }
  for (int d = 32; d > 0; d >>= 1) s += __shfl_xor(s, d, 64);
  __shared__ int wred[4];
  int lane = t & 63, wv = t >> 6;
  if (lane == 0) wred[wv] = s;
  __syncthreads();
  if (t == 0) bsum[blockIdx.x] = wred[0] + wred[1] + wred[2] + wred[3];
}

__global__ void k_scan_mid(int* __restrict__ bsum, int m) {
  int t = threadIdx.x;
  int v = (t < m) ? bsum[t] : 0;
  int lane = t & 63, wv = t >> 6;
  int x = v;
  for (int d = 1; d < 64; d <<= 1) { int y = __shfl_up(x, d, 64); if (lane >= d) x += y; }
  __shared__ int wsum[4];
  if (lane == 63) wsum[wv] = x;
  __syncthreads();
  int add = 0;
  for (int i = 0; i < wv; i++) add += wsum[i];
  int ex = add + x - v;
  if (t < m) bsum[t] = ex;
}

__global__ void k_scan_final(const int* __restrict__ cnt, const int* __restrict__ bsum,
                             int* __restrict__ off, int n) {
  int t = threadIdx.x;
  int base = blockIdx.x * 1024 + t * 4;
  int vals[4]; int s = 0;
#pragma unroll
  for (int i = 0; i < 4; i++) {
    int j = base + i;
    vals[i] = (j < n) ? cnt[j] : 0;
    s += vals[i];
  }
  int lane = t & 63, wv = t >> 6;
  int x = s;
  for (int d = 1; d < 64; d <<= 1) { int y = __shfl_up(x, d, 64); if (lane >= d) x += y; }
  __shared__ int wsum[4];
  if (lane == 63) wsum[wv] = x;
  __syncthreads();
  int add = 0;
  for (int i = 0; i < wv; i++) add += wsum[i];
  int run = add + x - s + bsum[blockIdx.x];
#pragma unroll
  for (int i = 0; i < 4; i++) {
    int j = base + i;
    if (j < n) off[j] = run;
    run += vals[i];
  }
}

__global__ void k_copyint(const int* __restrict__ a, int* __restrict__ b, int n) {
  int i = blockIdx.x * blockDim.x + threadIdx.x;
  if (i < n) b[i] = a[i];
}

__global__ void k_scatter(const int* __restrict__ s1, const int* __restrict__ d1,
                          const int* __restrict__ s2, const int* __restrict__ d2,
                          int* __restrict__ cur1, int* __restrict__ cur2,
                          int* __restrict__ o1, int* __restrict__ o2) {
  int e = blockIdx.x * blockDim.x + threadIdx.x;
  if (e >= NE) return;
  int p1 = atomicAdd(&cur1[d1[e]], 1);
  o1[p1] = s1[e];
  int p2 = atomicAdd(&cur2[d2[e]], 1);
  o2[p2] = s2[e];
}

// ---------------- merged P-GEMM (bf16 in/out): P = S @ Wt^T ----------------
// A direct from global bf16 state; W staged swizzled; C bounced via LDS, bf16 out.
__global__ __launch_bounds__(256) void k_gemmP(
    const u16* __restrict__ S1, const u16* __restrict__ Wt1, u16* __restrict__ P1,
    int M1, int tiles1,
    const u16* __restrict__ S2, const u16* __restrict__ Wt2, u16* __restrict__ P2,
    int M2) {
  __shared__ __align__(16) u16 Wls[128 * 128];  // 32KB; reused as C (64x136)
  const u16* S; const u16* Wt; u16* P; int M, bm;
  if ((int)blockIdx.x < tiles1) { S = S1; Wt = Wt1; P = P1; M = M1; bm = blockIdx.x * 64; }
  else { S = S2; Wt = Wt2; P = P2; M = M2; bm = (blockIdx.x - tiles1) * 64; }
  const int tid = threadIdx.x, wv = tid >> 6, lane = tid & 63;
  const int lrow = lane & 15, quad = lane >> 4;
#pragma unroll
  for (int i = 0; i < 8; i++) {  // stage W swizzled
    int task = i * 256 + tid;
    int col = task >> 4, gr = task & 15;
    uint4 v = *(const uint4*)(Wt + (size_t)col * 128 + gr * 8);
    *(uint4*)(Wls + (size_t)col * 128 + ((gr ^ (col & 15)) * 8)) = v;
  }
  const int arow = bm + wv * 16 + lrow;
  const bool arv = arow < M;
  const bf16x8 zv = {0, 0, 0, 0, 0, 0, 0, 0};
  bf16x8 a[4];
#pragma unroll
  for (int ks = 0; ks < 4; ks++)
    a[ks] = arv ? *(const bf16x8*)(S + (size_t)arow * 128 + quad * 8 + ks * 32) : zv;
  __syncthreads();
  floatx4 acc[8];
#pragma unroll
  for (int ct = 0; ct < 8; ct++) acc[ct] = {0.f, 0.f, 0.f, 0.f};
#pragma unroll
  for (int ks = 0; ks < 4; ks++) {
#pragma unroll
    for (int ct = 0; ct < 8; ct++) {
      int col = ct * 16 + lrow;
      bf16x8 b = *(const bf16x8*)(Wls + (size_t)col * 128 + (((4 * ks + quad) ^ lrow) * 8));
      acc[ct] = __builtin_amdgcn_mfma_f32_16x16x32_bf16(a[ks], b, acc[ct], 0, 0, 0);
    }
  }
  __syncthreads();  // W reads done; reuse as C
  u16* Cls = Wls;   // 64 x 136
#pragma unroll
  for (int ct = 0; ct < 8; ct++) {
    int col = ct * 16 + lrow;
#pragma unroll
    for (int reg = 0; reg < 4; reg++) {
      int lr = wv * 16 + quad * 4 + reg;
      Cls[(size_t)lr * 136 + col] = f2bf(acc[ct][reg]);
    }
  }
  __syncthreads();
#pragma unroll
  for (int i = 0; i < 4; i++) {  // coalesced bf16 write-out
    int task = i * 256 + tid;
    int row = task >> 4, c8 = task & 15;
    int gr2 = bm + row;
    if (gr2 < M)
      *(uint4*)(P + (size_t)gr2 * 128 + c8 * 8) = *(const uint4*)(Cls + (size_t)row * 136 + c8 * 8);
  }
}

// ---------------- merged fused Q-GEMM + gather-mean (bf16 in/out) ----------------
__global__ __launch_bounds__(256) void k_qgather(
    const u16* __restrict__ S1, const u16* __restrict__ Wb1, const float* __restrict__ bias1,
    const u16* __restrict__ P1g, const int* __restrict__ srcs1g,
    const int* __restrict__ off1g, const int* __restrict__ cnt1g,
    u16* __restrict__ out1, int n1, int tiles1,
    const u16* __restrict__ S2, const u16* __restrict__ Wb2, const float* __restrict__ bias2,
    const u16* __restrict__ P2g, const int* __restrict__ srcs2g,
    const int* __restrict__ off2g, const int* __restrict__ cnt2g,
    u16* __restrict__ out2, int n2) {
  __shared__ __align__(16) char smem[64 * 132 * 4];  // 33792 B
  u16* Wls = (u16*)smem;
  float* Qls = (float*)smem;
  const u16* S; const u16* Wb; const float* bias; const u16* P;
  const int* srcs; const int* off; const int* cnt; u16* outm; int nnodes, bm;
  if ((int)blockIdx.x < tiles1) {
    S = S1; Wb = Wb1; bias = bias1; P = P1g; srcs = srcs1g; off = off1g; cnt = cnt1g;
    outm = out1; nnodes = n1; bm = blockIdx.x * 64;
  } else {
    S = S2; Wb = Wb2; bias = bias2; P = P2g; srcs = srcs2g; off = off2g; cnt = cnt2g;
    outm = out2; nnodes = n2; bm = (blockIdx.x - tiles1) * 64;
  }
  const int tid = threadIdx.x, wv = tid >> 6, lane = tid & 63;
  const int lrow = lane & 15, quad = lane >> 4;
#pragma unroll
  for (int i = 0; i < 8; i++) {  // stage W swizzled
    int task = i * 256 + tid;
    int col = task >> 4, gr = task & 15;
    uint4 v = *(const uint4*)(Wb + (size_t)col * 128 + gr * 8);
    *(uint4*)(Wls + (size_t)col * 128 + ((gr ^ (col & 15)) * 8)) = v;
  }
  const int arow = bm + wv * 16 + lrow;
  const bool arv = arow < nnodes;
  const bf16x8 zv = {0, 0, 0, 0, 0, 0, 0, 0};
  bf16x8 a[4];
#pragma unroll
  for (int ks = 0; ks < 4; ks++)
    a[ks] = arv ? *(const bf16x8*)(S + (size_t)arow * 128 + quad * 8 + ks * 32) : zv;
  __syncthreads();
  floatx4 acc[8];
#pragma unroll
  for (int ct = 0; ct < 8; ct++) acc[ct] = {0.f, 0.f, 0.f, 0.f};
#pragma unroll
  for (int ks = 0; ks < 4; ks++) {
#pragma unroll
    for (int ct = 0; ct < 8; ct++) {
      int col = ct * 16 + lrow;
      bf16x8 b = *(const bf16x8*)(Wls + (size_t)col * 128 + (((4 * ks + quad) ^ lrow) * 8));
      acc[ct] = __builtin_amdgcn_mfma_f32_16x16x32_bf16(a[ks], b, acc[ct], 0, 0, 0);
    }
  }
  __syncthreads();  // W reads done; reuse smem as Q (fp32, stride 132)
#pragma unroll
  for (int ct = 0; ct < 8; ct++) {
    int col = ct * 16 + lrow;
    float bv = bias[col];
#pragma unroll
    for (int reg = 0; reg < 4; reg++) {
      int lr = wv * 16 + quad * 4 + reg;
      Qls[(size_t)lr * 132 + col] = acc[ct][reg] + bv;
    }
  }
  __syncthreads();
  // gather: 64 nodes x 16 col-granules (8 bf16 each) = 1024 tasks
#pragma unroll
  for (int it = 0; it < 4; it++) {
    int task = it * 256 + tid;
    int nl = task >> 4, c8 = (task & 15) << 3;
    int node = bm + nl;
    if (node >= nnodes) continue;
    const float* qp = Qls + (size_t)nl * 132 + c8;
    float4 qa = *(const float4*)(qp);
    float4 qb = *(const float4*)(qp + 4);
    float q[8] = {qa.x, qa.y, qa.z, qa.w, qb.x, qb.y, qb.z, qb.w};
    float acg[8] = {0.f, 0.f, 0.f, 0.f, 0.f, 0.f, 0.f, 0.f};
    int o = off[node], n = cnt[node];
    int i = 0;
    for (; i + 4 <= n; i += 4) {
      int s0 = srcs[o + i], s1 = srcs[o + i + 1], s2 = srcs[o + i + 2], s3 = srcs[o + i + 3];
      uint4 v0 = *(const uint4*)(P + (size_t)s0 * 128 + c8);
      uint4 v1 = *(const uint4*)(P + (size_t)s1 * 128 + c8);
      uint4 v2 = *(const uint4*)(P + (size_t)s2 * 128 + c8);
      uint4 v3 = *(const uint4*)(P + (size_t)s3 * 128 + c8);
      unsigned w[16] = {v0.x, v0.y, v0.z, v0.w, v1.x, v1.y, v1.z, v1.w,
                        v2.x, v2.y, v2.z, v2.w, v3.x, v3.y, v3.z, v3.w};
#pragma unroll
      for (int e = 0; e < 4; e++)
#pragma unroll
        for (int k = 0; k < 4; k++) {
          unsigned ww = w[e * 4 + k];
          float lo = __uint_as_float(ww << 16);
          float hi = __uint_as_float(ww & 0xffff0000u);
          acg[2 * k] += fmaxf(lo + q[2 * k], 0.f);
          acg[2 * k + 1] += fmaxf(hi + q[2 * k + 1], 0.f);
        }
    }
    for (; i < n; i++) {
      int s0 = srcs[o + i];
      uint4 v0 = *(const uint4*)(P + (size_t)s0 * 128 + c8);
      unsigned w[4] = {v0.x, v0.y, v0.z, v0.w};
#pragma unroll
      for (int k = 0; k < 4; k++) {
        unsigned ww = w[k];
        float lo = __uint_as_float(ww << 16);
        float hi = __uint_as_float(ww & 0xffff0000u);
        acg[2 * k] += fmaxf(lo + q[2 * k], 0.f);
        acg[2 * k + 1] += fmaxf(hi + q[2 * k + 1], 0.f);
      }
    }
    float inv = 1.f / fmaxf((float)n, 1.f);
    bf16x8 ov;
#pragma unroll
    for (int k = 0; k < 8; k++) ov[k] = (short)f2bf(acg[k] * inv);
    *(bf16x8*)(outm + (size_t)node * 128 + c8) = ov;
  }
}

// ---------------- merged fused GRU (bf16 state I/O): 128 rows/block ----------------
__global__ __launch_bounds__(256, 2) void k_gru_fused(
    const u16* __restrict__ X1, const u16* __restrict__ Wx1, const u16* __restrict__ Wh1,
    const float* __restrict__ b1, u16* __restrict__ H1, int r1, int tiles1,
    const u16* __restrict__ X2, const u16* __restrict__ Wx2, const u16* __restrict__ Wh2,
    const float* __restrict__ b2, u16* __restrict__ H2, int r2) {
  __shared__ __align__(16) u16 Ls[6 * 32 * 128];  // 49152 B
  const u16* X; const u16* Wxb; const u16* Whb; const float* bias; u16* H;
  int rows, bm;
  if ((int)blockIdx.x < tiles1) {
    X = X1; Wxb = Wx1; Whb = Wh1; bias = b1; H = H1; rows = r1; bm = blockIdx.x * 128;
  } else {
    X = X2; Wxb = Wx2; Whb = Wh2; bias = b2; H = H2; rows = r2;
    bm = (blockIdx.x - tiles1) * 128;
  }
  const int tid = threadIdx.x, wv = tid >> 6, lane = tid & 63;
  const int lrow = lane & 15, quad = lane >> 4;
  const bf16x8 zv = {0, 0, 0, 0, 0, 0, 0, 0};
  bf16x8 ax[2][4], ah[2][4];
#pragma unroll
  for (int tile = 0; tile < 2; tile++) {
    int arow = bm + tile * 64 + wv * 16 + lrow;
    bool arv = arow < rows;
    const u16* xp = X + (size_t)arow * 128 + quad * 8;
    const u16* hp = H + (size_t)arow * 128 + quad * 8;
#pragma unroll
    for (int ks = 0; ks < 4; ks++) {
      ax[tile][ks] = arv ? *(const bf16x8*)(xp + ks * 32) : zv;
      ah[tile][ks] = arv ? *(const bf16x8*)(hp + ks * 32) : zv;
    }
  }
  for (int ch = 0; ch < 4; ch++) {
    __syncthreads();
#pragma unroll
    for (int p = 0; p < 2; p++) {
      uint4 v[6];
#pragma unroll
      for (int j = 0; j < 6; j++) {
        int task = (p * 6 + j) * 256 + tid;
        int seg = task >> 9, rem = task & 511;
        int col = rem >> 4, g = rem & 15;
        const u16* gsrc = (seg < 3 ? Wxb : Whb) +
                          (size_t)((seg < 3 ? seg : seg - 3) * 128 + ch * 32 + col) * 128 + g * 8;
        v[j] = *(const uint4*)gsrc;
      }
#pragma unroll
      for (int j = 0; j < 6; j++) {
        int task = (p * 6 + j) * 256 + tid;
        int seg = task >> 9, rem = task & 511;
        int col = rem >> 4, g = rem & 15;
        *(uint4*)(Ls + (size_t)(seg * 32 + col) * 128 + ((g ^ (col & 15)) * 8)) = v[j];
      }
    }
    __syncthreads();
    floatx4 acc[2][2][3][2];
#pragma unroll
    for (int tile = 0; tile < 2; tile++)
#pragma unroll
      for (int t = 0; t < 2; t++)
#pragma unroll
        for (int g = 0; g < 3; g++) {
          acc[tile][t][g][0] = {0.f, 0.f, 0.f, 0.f};
          acc[tile][t][g][1] = {0.f, 0.f, 0.f, 0.f};
        }
#pragma unroll
    for (int ks = 0; ks < 4; ks++) {
      int posu = ((4 * ks + quad) ^ lrow) * 8;
#pragma unroll
      for (int t = 0; t < 2; t++) {
        int cIdx = t * 16 + lrow;
#pragma unroll
        for (int g = 0; g < 3; g++) {
          bf16x8 bx = *(const bf16x8*)(Ls + (size_t)(g * 32 + cIdx) * 128 + posu);
          bf16x8 bh = *(const bf16x8*)(Ls + (size_t)((3 + g) * 32 + cIdx) * 128 + posu);
          acc[0][t][g][0] = __builtin_amdgcn_mfma_f32_16x16x32_bf16(ax[0][ks], bx, acc[0][t][g][0], 0, 0, 0);
          acc[0][t][g][1] = __builtin_amdgcn_mfma_f32_16x16x32_bf16(ah[0][ks], bh, acc[0][t][g][1], 0, 0, 0);
          acc[1][t][g][0] = __builtin_amdgcn_mfma_f32_16x16x32_bf16(ax[1][ks], bx, acc[1][t][g][0], 0, 0, 0);
          acc[1][t][g][1] = __builtin_amdgcn_mfma_f32_16x16x32_bf16(ah[1][ks], bh, acc[1][t][g][1], 0, 0, 0);
        }
      }
    }
#pragma unroll
    for (int tile = 0; tile < 2; tile++) {
#pragma unroll
      for (int t = 0; t < 2; t++) {
        int hcol = ch * 32 + t * 16 + lrow;
        float bxz = bias[hcol];
        float bxr = bias[128 + hcol];
        float bxh = bias[256 + hcol];
        float bhz = bias[384 + hcol];
        float bhr = bias[384 + 128 + hcol];
        float bhh = bias[384 + 256 + hcol];
#pragma unroll
        for (int reg = 0; reg < 4; reg++) {
          int r = bm + tile * 64 + wv * 16 + quad * 4 + reg;
          if (r < rows) {
            float xz = acc[tile][t][0][0][reg] + bxz;
            float xr = acc[tile][t][1][0][reg] + bxr;
            float xh = acc[tile][t][2][0][reg] + bxh;
            float hz = acc[tile][t][0][1][reg] + bhz;
            float hr = acc[tile][t][1][1][reg] + bhr;
            float hh = acc[tile][t][2][1][reg] + bhh;
            float z = fsigmoid(xz + hz);
            float rr = fsigmoid(xr + hr);
            float hc = ftanh(xh + rr * hh);
            u16* hp2 = H + (size_t)r * 128 + hcol;
            float hold = bf2f(*hp2);
            *hp2 = f2bf(z * hold + (1.f - z) * hc);
          }
        }
      }
    }
  }
}

// ---------------- fully fused readout: 2 GEMMs + logits + softmax ----------------
__global__ __launch_bounds__(256) void k_readout2(
    const u16* __restrict__ S, const u16* __restrict__ W1b, const float* __restrict__ b1,
    const u16* __restrict__ W2b, const float* __restrict__ b2,
    const float* __restrict__ W3, const float* __restrict__ b3,
    float* __restrict__ out, int M) {
  __shared__ __align__(16) char smem[64 * 132 * 4];  // 33792 B
  u16* Wls = (u16*)smem;                 // phase1: W1 32KB swizzled
  u16* H1ls = (u16*)smem;                // phase2/3: 64 x 136 u16
  u16* W2ls = (u16*)(smem + 17408);      // 64 x 128 u16 = 16384B (17408+16384=33792)
  u16* H2ls = (u16*)smem;                // phase4/5: 64 x 72 u16 = 9216B
  float* W3ls = (float*)(smem + 9216);   // 960 fp32 = 3840B
  float* b3ls = (float*)(smem + 9216 + 3840);
  const int tid = threadIdx.x, wv = tid >> 6, lane = tid & 63;
  const int lrow = lane & 15, quad = lane >> 4;
  const int bm = blockIdx.x * 64;
  // phase 1: h1 = relu(S @ W1 + b1)
#pragma unroll
  for (int i = 0; i < 8; i++) {
    int task = i * 256 + tid;
    int col = task >> 4, gr = task & 15;
    uint4 v = *(const uint4*)(W1b + (size_t)col * 128 + gr * 8);
    *(uint4*)(Wls + (size_t)col * 128 + ((gr ^ (col & 15)) * 8)) = v;
  }
  const int arow = bm + wv * 16 + lrow;
  const bool arv = arow < M;
  const bf16x8 zv = {0, 0, 0, 0, 0, 0, 0, 0};
  bf16x8 a[4];
#pragma unroll
  for (int ks = 0; ks < 4; ks++)
    a[ks] = arv ? *(const bf16x8*)(S + (size_t)arow * 128 + quad * 8 + ks * 32) : zv;
  __syncthreads();
  floatx4 acc1[8];
#pragma unroll
  for (int ct = 0; ct < 8; ct++) acc1[ct] = {0.f, 0.f, 0.f, 0.f};
#pragma unroll
  for (int ks = 0; ks < 4; ks++) {
#pragma unroll
    for (int ct = 0; ct < 8; ct++) {
      int col = ct * 16 + lrow;
      bf16x8 b = *(const bf16x8*)(Wls + (size_t)col * 128 + (((4 * ks + quad) ^ lrow) * 8));
      acc1[ct] = __builtin_amdgcn_mfma_f32_16x16x32_bf16(a[ks], b, acc1[ct], 0, 0, 0);
    }
  }
  __syncthreads();
  // phase 2: bounce h1 (relu, bf16) + stage W2
#pragma unroll
  for (int ct = 0; ct < 8; ct++) {
    int col = ct * 16 + lrow;
    float bv = b1[col];
#pragma unroll
    for (int reg = 0; reg < 4; reg++) {
      int lr = wv * 16 + quad * 4 + reg;
      H1ls[(size_t)lr * 136 + col] = f2bf(fmaxf(acc1[ct][reg] + bv, 0.f));
    }
  }
#pragma unroll
  for (int i = 0; i < 4; i++) {
    int task = i * 256 + tid;
    int col = task >> 4, gr = task & 15;
    uint4 v = *(const uint4*)(W2b + (size_t)col * 128 + gr * 8);
    *(uint4*)(W2ls + (size_t)col * 128 + ((gr ^ (col & 15)) * 8)) = v;
  }
  __syncthreads();
  // phase 3: h2 = relu(h1 @ W2 + b2)
  bf16x8 a2[4];
#pragma unroll
  for (int ks = 0; ks < 4; ks++)
    a2[ks] = *(const bf16x8*)(H1ls + (size_t)(wv * 16 + lrow) * 136 + quad * 8 + ks * 32);
  floatx4 acc2[4];
#pragma unroll
  for (int ct = 0; ct < 4; ct++) acc2[ct] = {0.f, 0.f, 0.f, 0.f};
#pragma unroll
  for (int ks = 0; ks < 4; ks++) {
#pragma unroll
    for (int ct = 0; ct < 4; ct++) {
      int col = ct * 16 + lrow;
      bf16x8 b = *(const bf16x8*)(W2ls + (size_t)col * 128 + (((4 * ks + quad) ^ lrow) * 8));
      acc2[ct] = __builtin_amdgcn_mfma_f32_16x16x32_bf16(a2[ks], b, acc2[ct], 0, 0, 0);
    }
  }
  __syncthreads();
  // phase 4: bounce h2 (relu, bf16) + stage W3/b3
#pragma unroll
  for (int ct = 0; ct < 4; ct++) {
    int col = ct * 16 + lrow;
    float bv = b2[col];
#pragma unroll
    for (int reg = 0; reg < 4; reg++) {
      int lr = wv * 16 + quad * 4 + reg;
      H2ls[(size_t)lr * 72 + col] = f2bf(fmaxf(acc2[ct][reg] + bv, 0.f));
    }
  }
  for (int l = tid; l < 960; l += 256) W3ls[l] = W3[l];
  if (tid < 15) b3ls[tid] = b3[tid];
  __syncthreads();
  // phase 5: logits + softmax (wave 0, one row per lane)
  if (tid < 64) {
    int row = tid, gr2 = bm + row;
    if (gr2 < M) {
      float lg[15];
#pragma unroll
      for (int c = 0; c < 15; c++) lg[c] = b3ls[c];
      for (int k = 0; k < 64; k++) {
        float hk = bf2f(H2ls[(size_t)row * 72 + k]);
#pragma unroll
        for (int c = 0; c < 15; c++) lg[c] += hk * W3ls[k * 15 + c];
      }
      float m = lg[0];
#pragma unroll
      for (int c = 1; c < 15; c++) m = fmaxf(m, lg[c]);
      float ssum = 0.f;
#pragma unroll
      for (int c = 0; c < 15; c++) { lg[c] = __expf(lg[c] - m); ssum += lg[c]; }
      float inv = 1.f / ssum;
#pragma unroll
      for (int c = 0; c < 15; c++) out[(size_t)gr2 * 15 + c] = lg[c] * inv;
    }
  }
}

// ---------------- launch ----------------
extern "C" void kernel_launch(void* const* d_in, const int* in_sizes, int n_in,
                              void* d_out, int out_size, void* d_ws, size_t ws_size,
                              hipStream_t stream) {
  const float* feat = (const float*)d_in[0];
  const int* src1 = (const int*)d_in[1];
  const int* dst1 = (const int*)d_in[2];
  const int* src2 = (const int*)d_in[3];
  const int* dst2 = (const int*)d_in[4];
  const float* Wm1 = (const float*)d_in[5];
  const float* bm1 = (const float*)d_in[6];
  const float* Wm2 = (const float*)d_in[7];
  const float* bm2 = (const float*)d_in[8];
  const float* gik = (const float*)d_in[9];
  const float* gir = (const float*)d_in[10];
  const float* gib = (const float*)d_in[11];
  const float* gck = (const float*)d_in[12];
  const float* gcr = (const float*)d_in[13];
  const float* gcb = (const float*)d_in[14];
  const float* Wr1 = (const float*)d_in[15];
  const float* br1 = (const float*)d_in[16];
  const float* Wr2 = (const float*)d_in[17];
  const float* br2 = (const float*)d_in[18];
  const float* Wr3 = (const float*)d_in[19];
  const float* br3 = (const float*)d_in[20];
  float* out = (float*)d_out;

  // ---- workspace layout (u16 units) ----
  u16* w16 = (u16*)d_ws;
  size_t o = 0;
  u16* ip_state = w16 + o;   o += (size_t)N_IP * D;     // 2.56M
  u16* conn_state = w16 + o; o += (size_t)N_CONN * D;   // 12.8M
  u16* sum1 = w16 + o;       o += (size_t)N_CONN * D;
  u16* sum2 = w16 + o;       o += (size_t)N_IP * D;
  u16* P1 = w16 + o;         o += (size_t)N_IP * D;
  u16* P2 = w16 + o;         o += (size_t)N_CONN * D;
  u16* gikb = w16 + o;       o += 49152;
  u16* girb = w16 + o;       o += 49152;
  u16* gckb = w16 + o;       o += 49152;
  u16* gcrb = w16 + o;       o += 49152;
  u16* wm1b = w16 + o;       o += 16384;  // Wm1 bottom [col][k]
  u16* wm2b = w16 + o;       o += 16384;
  u16* wm1t = w16 + o;       o += 16384;  // Wm1 top
  u16* wm2t = w16 + o;       o += 16384;
  u16* wr1b = w16 + o;       o += 16384;
  u16* wr2b = w16 + o;       o += 8192;
  int* ip = (int*)(w16 + o);  // o is even -> 4B aligned
  int* cnt1 = ip;  ip += N_CONN;
  int* cnt2 = ip;  ip += N_IP;
  int* off1 = ip;  ip += N_CONN;
  int* off2 = ip;  ip += N_IP;
  int* cur1 = ip;  ip += N_CONN;
  int* cur2 = ip;  ip += N_IP;
  int* srcs1 = ip; ip += NE;
  int* srcs2 = ip; ip += NE;
  int* bsum1 = ip; ip += 256;
  int* bsum2 = ip; ip += 256;

  const int BT = 256;

  // ---- init states + weight prep ----
  k_fill_bf1<<<(N_IP * D / 2 + BT - 1) / BT, BT, 0, stream>>>((unsigned*)ip_state, N_IP * D / 2);
  k_init_conn_bf<<<(N_CONN * D + BT - 1) / BT, BT, 0, stream>>>(conn_state, feat);
  k_prep_w<<<(384 * 128 + BT - 1) / BT, BT, 0, stream>>>(gik, gikb);
  k_prep_w<<<(384 * 128 + BT - 1) / BT, BT, 0, stream>>>(gir, girb);
  k_prep_w<<<(384 * 128 + BT - 1) / BT, BT, 0, stream>>>(gck, gckb);
  k_prep_w<<<(384 * 128 + BT - 1) / BT, BT, 0, stream>>>(gcr, gcrb);
  k_prep_w128<<<64, BT, 0, stream>>>(Wm1, wm1b, 128);
  k_prep_w128<<<64, BT, 0, stream>>>(Wm2, wm2b, 128);
  k_prep_w128<<<64, BT, 0, stream>>>(Wm1, wm1t, 0);
  k_prep_w128<<<64, BT, 0, stream>>>(Wm2, wm2t, 0);
  k_prep_w128<<<64, BT, 0, stream>>>(Wr1, wr1b, 0);
  k_prep_wr2<<<32, BT, 0, stream>>>(Wr2, wr2b);

  // ---- build CSR ----
  hipMemsetAsync(cnt1, 0, (size_t)(N_CONN + N_IP) * sizeof(int), stream);
  k_count<<<(NE + BT - 1) / BT, BT, 0, stream>>>(dst1, dst2, cnt1, cnt2);
  const int nb1 = (N_CONN + 1023) / 1024, nb2 = (N_IP + 1023) / 1024;
  k_scan_part<<<nb1, 256, 0, stream>>>(cnt1, bsum1, N_CONN);
  k_scan_part<<<nb2, 256, 0, stream>>>(cnt2, bsum2, N_IP);
  k_scan_mid<<<1, 256, 0, stream>>>(bsum1, nb1);
  k_scan_mid<<<1, 256, 0, stream>>>(bsum2, nb2);
  k_scan_final<<<nb1, 256, 0, stream>>>(cnt1, bsum1, off1, N_CONN);
  k_scan_final<<<nb2, 256, 0, stream>>>(cnt2, bsum2, off2, N_IP);
  k_copyint<<<(N_CONN + N_IP + BT - 1) / BT, BT, 0, stream>>>(off1, cur1, N_CONN + N_IP);
  k_scatter<<<(NE + BT - 1) / BT, BT, 0, stream>>>(src1, dst1, src2, dst2,
                                                   cur1, cur2, srcs1, srcs2);

  const int t64ip = (N_IP + 63) / 64;       // 313
  const int t64cn = (N_CONN + 63) / 64;     // 1563
  const int t128ip = (N_IP + 127) / 128;    // 157
  const int t128cn = (N_CONN + 127) / 128;  // 782

  for (int t = 0; t < T_ROUNDS; t++) {
    k_gemmP<<<t64ip + t64cn, 256, 0, stream>>>(ip_state, wm1t, P1, N_IP, t64ip,
                                               conn_state, wm2t, P2, N_CONN);
    k_qgather<<<t64cn + t64ip, 256, 0, stream>>>(
        conn_state, wm1b, bm1, P1, srcs1, off1, cnt1, sum1, N_CONN, t64cn,
        ip_state, wm2b, bm2, P2, srcs2, off2, cnt2, sum2, N_IP);
    k_gru_fused<<<t128cn + t128ip, 256, 0, stream>>>(
        sum1, gckb, gcrb, gcb, conn_state, N_CONN, t128cn,
        sum2, gikb, girb, gib, ip_state, N_IP);
  }

  k_readout2<<<t64cn, 256, 0, stream>>>(conn_state, wr1b, br1, wr2b, br2,
                                        Wr3, br3, out, N_CONN);
}